// Round 2
// baseline (1083.360 us; speedup 1.0000x reference)
//
#include <hip/hip_runtime.h>
#include <math.h>

#define NN 150000      // nodes
#define NE 4800000     // edges (without self loops)
#define HD 16          // hidden dim

// ---------------- degree / norm ----------------

__global__ void k_init_deg(float* __restrict__ deg) {
    int v = blockIdx.x * blockDim.x + threadIdx.x;
    if (v < NN) deg[v] = 1.0f;   // self loop
}

__global__ void k_accum_deg(const int* __restrict__ dst, float* __restrict__ deg) {
    int e = blockIdx.x * blockDim.x + threadIdx.x;
    if (e < NE) atomicAdd(&deg[dst[e]], 1.0f);
}

__global__ void k_rsqrt_inplace(float* __restrict__ d) {
    int v = blockIdx.x * blockDim.x + threadIdx.x;
    if (v < NN) d[v] = rsqrtf(d[v]);
}

// ---------------- layer 1: t = (x @ W_in) * dinv ----------------

__global__ void k_transform_in(const float* __restrict__ x, const float* __restrict__ W,
                               const float* __restrict__ dinv, float* __restrict__ t) {
    int gid = blockIdx.x * blockDim.x + threadIdx.x;
    if (gid >= NN * HD) return;
    int v = gid >> 4, j = gid & 15;
    float s = x[v * 3 + 0] * W[j] + x[v * 3 + 1] * W[HD + j] + x[v * 3 + 2] * W[2 * HD + j];
    t[gid] = s * dinv[v];
}

// ---------------- edge scatter, 16 features (16 threads / edge) ----------------

__global__ void k_scatter16(const int* __restrict__ src, const int* __restrict__ dst,
                            const float* __restrict__ t, float* __restrict__ acc) {
    int gid = blockIdx.x * blockDim.x + threadIdx.x;   // < NE*16 = 76.8M, fits int
    if (gid >= NE * HD) return;
    int e = gid >> 4, j = gid & 15;
    int s = src[e], d = dst[e];
    atomicAdd(&acc[d * HD + j], t[s * HD + j]);
}

// ---------------- finalize layer i (relu) fused with transform of layer i+1 ----------------
// h[v] = relu((acc[v] + t[v]) * dinv[v] + b); tnext[v] = (h[v] @ Wn) * dinv[v]
// NOTE: tnext must be a DIFFERENT buffer than t (no aliasing).

__global__ void k_finalize_mid(const float* __restrict__ acc, const float* __restrict__ t,
                               const float* __restrict__ dinv, const float* __restrict__ b,
                               const float* __restrict__ Wn, float* __restrict__ tnext) {
    __shared__ float sW[HD * HD];
    if (threadIdx.x < HD * HD) sW[threadIdx.x] = Wn[threadIdx.x];
    __syncthreads();
    int v = blockIdx.x * blockDim.x + threadIdx.x;
    if (v >= NN) return;
    float di = dinv[v];
    float h[HD];
    const float4* a4 = (const float4*)(acc + (size_t)v * HD);
    const float4* t4 = (const float4*)(t + (size_t)v * HD);
#pragma unroll
    for (int q = 0; q < 4; ++q) {
        float4 a = a4[q], tt = t4[q];
        h[4 * q + 0] = fmaxf((a.x + tt.x) * di + b[4 * q + 0], 0.0f);
        h[4 * q + 1] = fmaxf((a.y + tt.y) * di + b[4 * q + 1], 0.0f);
        h[4 * q + 2] = fmaxf((a.z + tt.z) * di + b[4 * q + 2], 0.0f);
        h[4 * q + 3] = fmaxf((a.w + tt.w) * di + b[4 * q + 3], 0.0f);
    }
    float4* o4 = (float4*)(tnext + (size_t)v * HD);
#pragma unroll
    for (int q = 0; q < 4; ++q) {
        float4 o;
        float* op = (float*)&o;
#pragma unroll
        for (int jj = 0; jj < 4; ++jj) {
            int j = 4 * q + jj;
            float s = 0.0f;
#pragma unroll
            for (int k = 0; k < HD; ++k) s += h[k] * sW[k * HD + j];
            op[jj] = s * di;
        }
        o4[q] = o;
    }
}

// ---------------- finalize layer 2 (relu) fused with output transform (H -> 1) ----------------

__global__ void k_finalize_out(const float* __restrict__ acc, const float* __restrict__ t,
                               const float* __restrict__ dinv, const float* __restrict__ b,
                               const float* __restrict__ Wout, float* __restrict__ t3) {
    __shared__ float sW[HD];
    __shared__ float sB[HD];
    if (threadIdx.x < HD) { sW[threadIdx.x] = Wout[threadIdx.x]; sB[threadIdx.x] = b[threadIdx.x]; }
    __syncthreads();
    int v = blockIdx.x * blockDim.x + threadIdx.x;
    if (v >= NN) return;
    float di = dinv[v];
    float s = 0.0f;
    const float4* a4 = (const float4*)(acc + (size_t)v * HD);
    const float4* t4 = (const float4*)(t + (size_t)v * HD);
#pragma unroll
    for (int q = 0; q < 4; ++q) {
        float4 a = a4[q], tt = t4[q];
        float h0 = fmaxf((a.x + tt.x) * di + sB[4 * q + 0], 0.0f);
        float h1 = fmaxf((a.y + tt.y) * di + sB[4 * q + 1], 0.0f);
        float h2 = fmaxf((a.z + tt.z) * di + sB[4 * q + 2], 0.0f);
        float h3 = fmaxf((a.w + tt.w) * di + sB[4 * q + 3], 0.0f);
        s += h0 * sW[4 * q + 0] + h1 * sW[4 * q + 1] + h2 * sW[4 * q + 2] + h3 * sW[4 * q + 3];
    }
    t3[v] = s * di;
}

// ---------------- output layer scatter (1 feature) ----------------

__global__ void k_scatter1(const int* __restrict__ src, const int* __restrict__ dst,
                           const float* __restrict__ t3, float* __restrict__ acc) {
    int e = blockIdx.x * blockDim.x + threadIdx.x;
    if (e < NE) atomicAdd(&acc[dst[e]], t3[src[e]]);
}

__global__ void k_final(const float* __restrict__ acc, const float* __restrict__ t3,
                        const float* __restrict__ dinv, const float* __restrict__ b_out,
                        float* __restrict__ out) {
    int v = blockIdx.x * blockDim.x + threadIdx.x;
    if (v >= NN) return;
    float z = (acc[v] + t3[v]) * dinv[v] + b_out[0];
    out[v] = 1.0f / (1.0f + expf(-z));
}

extern "C" void kernel_launch(void* const* d_in, const int* in_sizes, int n_in,
                              void* d_out, int out_size, void* d_ws, size_t ws_size,
                              hipStream_t stream) {
    const float* x     = (const float*)d_in[0];
    const int*   ei    = (const int*)d_in[1];   // [2, E] int32 (harness converts integer to int32)
    const float* W_in  = (const float*)d_in[2]; // [3,16]
    const float* b_in  = (const float*)d_in[3]; // [16]
    const float* W_mid = (const float*)d_in[4]; // [1,16,16]
    const float* b_mid = (const float*)d_in[5]; // [1,16]
    const float* W_out = (const float*)d_in[6]; // [16,1]
    const float* b_out = (const float*)d_in[7]; // [1]
    float* out = (float*)d_out;

    float* ws   = (float*)d_ws;
    float* dinv = ws;                 // N
    float* tA   = ws + NN;            // 16N
    float* tB   = tA + (size_t)16 * NN; // 16N
    float* acc  = tB + (size_t)16 * NN; // 16N

    const int* src = ei;
    const int* dst = ei + NE;

    const int B = 256;
    const int gN  = (NN + B - 1) / B;
    const int gE  = (NE + B - 1) / B;
    const int gNH = (NN * HD + B - 1) / B;
    const int gEH = (NE * HD + B - 1) / B;

    // degree -> dinv
    k_init_deg<<<gN, B, 0, stream>>>(dinv);
    k_accum_deg<<<gE, B, 0, stream>>>(dst, dinv);
    k_rsqrt_inplace<<<gN, B, 0, stream>>>(dinv);

    // layer 1: 3 -> 16
    k_transform_in<<<gNH, B, 0, stream>>>(x, W_in, dinv, tA);
    hipMemsetAsync(acc, 0, (size_t)NN * HD * sizeof(float), stream);
    k_scatter16<<<gEH, B, 0, stream>>>(src, dst, tA, acc);
    k_finalize_mid<<<gN, B, 0, stream>>>(acc, tA, dinv, b_in, W_mid, tB);

    // layer 2: 16 -> 16
    hipMemsetAsync(acc, 0, (size_t)NN * HD * sizeof(float), stream);
    k_scatter16<<<gEH, B, 0, stream>>>(src, dst, tB, acc);
    k_finalize_out<<<gN, B, 0, stream>>>(acc, tB, dinv, b_mid, W_out, tA);

    // layer 3: 16 -> 1, then sigmoid
    hipMemsetAsync(acc, 0, (size_t)NN * sizeof(float), stream);
    k_scatter1<<<gE, B, 0, stream>>>(src, dst, tA, acc);
    k_final<<<gN, B, 0, stream>>>(acc, tA, dinv, b_out, out);
}

// Round 3
// 844.434 us; speedup vs baseline: 1.2829x; 1.2829x over previous
//
#include <hip/hip_runtime.h>
#include <math.h>

#define NN 150000      // nodes (== 16 * 9375, exact)
#define NE 4800000     // edges (without self loops)
#define HD 16          // hidden dim
#define NB 586         // ceil(NN / 256)

// ---- bf16 helpers (bit-level, round-to-nearest-even) ----
__device__ __forceinline__ float bf2f(unsigned short u) {
    return __uint_as_float(((unsigned int)u) << 16);
}
__device__ __forceinline__ unsigned short f2bf(float f) {
    unsigned int x = __float_as_uint(f);
    return (unsigned short)((x + 0x7FFFu + ((x >> 16) & 1u)) >> 16);
}

// ---------------- CSR build: histogram ----------------
__global__ void k_hist(const int* __restrict__ dst, int* __restrict__ cnt) {
    int e = blockIdx.x * blockDim.x + threadIdx.x;
    if (e < NE) atomicAdd(&cnt[dst[e]], 1);
}

// ---------------- CSR build: per-block sums ----------------
__global__ void k_bsum(const int* __restrict__ cnt, int* __restrict__ bsum) {
    __shared__ int s[256];
    int t = threadIdx.x;
    int i = blockIdx.x * 256 + t;
    int v = (i < NN) ? cnt[i] : 0;
    s[t] = v;
    __syncthreads();
    for (int off = 128; off > 0; off >>= 1) {
        if (t < off) s[t] += s[t + off];
        __syncthreads();
    }
    if (t == 0) bsum[blockIdx.x] = s[0];
}

// ---------------- CSR build: scan block sums (1 block, 1024 thr) ----------------
__global__ void k_scan_bsum(int* __restrict__ bsum) {
    __shared__ int s[1024];
    int t = threadIdx.x;
    int v = (t < NB) ? bsum[t] : 0;
    s[t] = v;
    __syncthreads();
    for (int off = 1; off < 1024; off <<= 1) {
        int x = (t >= off) ? s[t - off] : 0;
        __syncthreads();
        s[t] += x;
        __syncthreads();
    }
    if (t < NB) bsum[t] = s[t] - v;   // exclusive
}

// ---------------- CSR build: final scan -> row_start, fill, dinv ----------------
__global__ void k_scan_final(const int* __restrict__ cnt, const int* __restrict__ bsum,
                             int* __restrict__ row_start, int* __restrict__ fill,
                             float* __restrict__ dinv) {
    __shared__ int s[256];
    int t = threadIdx.x;
    int i = blockIdx.x * 256 + t;
    int cv = (i < NN) ? cnt[i] : 0;
    s[t] = cv;
    __syncthreads();
    for (int off = 1; off < 256; off <<= 1) {
        int x = (t >= off) ? s[t - off] : 0;
        __syncthreads();
        s[t] += x;
        __syncthreads();
    }
    int excl = s[t] - cv + bsum[blockIdx.x];
    if (i < NN) {
        row_start[i] = excl;
        fill[i]      = excl;
        dinv[i]      = rsqrtf((float)cv + 1.0f);   // degree includes self loop
    }
    if (i == 0) row_start[NN] = NE;
}

// ---------------- CSR build: scatter src into dst-sorted order ----------------
__global__ void k_scatter_build(const int* __restrict__ src, const int* __restrict__ dst,
                                int* __restrict__ fill, int* __restrict__ ssrc) {
    int e = blockIdx.x * blockDim.x + threadIdx.x;
    if (e >= NE) return;
    int d = dst[e];
    int pos = atomicAdd(&fill[d], 1);
    ssrc[pos] = src[e];
}

// ---------------- layer 1 transform: t = (x @ W_in) * dinv  (bf16 out) ----------------
__global__ void k_transform_in(const float* __restrict__ x, const float* __restrict__ W,
                               const float* __restrict__ dinv, unsigned short* __restrict__ t) {
    int gid = blockIdx.x * blockDim.x + threadIdx.x;
    if (gid >= NN * HD) return;
    int v = gid >> 4, j = gid & 15;
    float s = x[v * 3 + 0] * W[j] + x[v * 3 + 1] * W[HD + j] + x[v * 3 + 2] * W[2 * HD + j];
    t[gid] = f2bf(s * dinv[v]);
}

// ---------------- fused gather + finalize(relu) + next transform (16 -> 16) ----------------
// 16 lanes per node; sum_j = sum_{e in N(v)} t[src_e][j] + t[v][j] (self loop)
// h_j = relu(sum_j * dinv[v] + b[j]);  tnext[v][j] = (sum_k h_k W[k][j]) * dinv[v]
__global__ void k_gather_mid(const int* __restrict__ row_start, const int* __restrict__ ssrc,
                             const unsigned short* __restrict__ t, const float* __restrict__ dinv,
                             const float* __restrict__ b, const float* __restrict__ W,
                             unsigned short* __restrict__ tnext) {
    __shared__ float sW[HD * HD];
    __shared__ float sh[256];
    int tid = threadIdx.x;
    sW[tid & 255] = W[tid & 255];   // block == 256 threads
    int v = blockIdx.x * 16 + (tid >> 4);
    int j = tid & 15;
    int e0 = row_start[v], e1 = row_start[v + 1];
    float sum = 0.0f;
    int e = e0;
    for (; e + 4 <= e1; e += 4) {
        int s0 = ssrc[e], s1 = ssrc[e + 1], s2 = ssrc[e + 2], s3 = ssrc[e + 3];
        sum += bf2f(t[s0 * HD + j]) + bf2f(t[s1 * HD + j])
             + bf2f(t[s2 * HD + j]) + bf2f(t[s3 * HD + j]);
    }
    for (; e < e1; ++e) sum += bf2f(t[ssrc[e] * HD + j]);
    sum += bf2f(t[v * HD + j]);                 // self loop
    float di = dinv[v];
    float h = fmaxf(sum * di + b[j], 0.0f);
    sh[tid] = h;
    __syncthreads();
    int g = (tid >> 4) << 4;                    // group base in sh
    float o = 0.0f;
#pragma unroll
    for (int k = 0; k < HD; ++k) o += sh[g + k] * sW[k * HD + j];
    tnext[v * HD + j] = f2bf(o * di);
}

// ---------------- fused gather + finalize(relu) + output dot (16 -> 1) ----------------
// t3[v] = (sum_j h_j * Wout[j]) * dinv[v]
__global__ void k_gather_out(const int* __restrict__ row_start, const int* __restrict__ ssrc,
                             const unsigned short* __restrict__ t, const float* __restrict__ dinv,
                             const float* __restrict__ b, const float* __restrict__ Wout,
                             float* __restrict__ t3) {
    int tid = threadIdx.x;
    int v = blockIdx.x * 16 + (tid >> 4);
    int j = tid & 15;
    int e0 = row_start[v], e1 = row_start[v + 1];
    float sum = 0.0f;
    int e = e0;
    for (; e + 4 <= e1; e += 4) {
        int s0 = ssrc[e], s1 = ssrc[e + 1], s2 = ssrc[e + 2], s3 = ssrc[e + 3];
        sum += bf2f(t[s0 * HD + j]) + bf2f(t[s1 * HD + j])
             + bf2f(t[s2 * HD + j]) + bf2f(t[s3 * HD + j]);
    }
    for (; e < e1; ++e) sum += bf2f(t[ssrc[e] * HD + j]);
    sum += bf2f(t[v * HD + j]);
    float di = dinv[v];
    float h = fmaxf(sum * di + b[j], 0.0f);
    float d = h * Wout[j];
    d += __shfl_xor(d, 1);
    d += __shfl_xor(d, 2);
    d += __shfl_xor(d, 4);
    d += __shfl_xor(d, 8);
    if (j == 0) t3[v] = d * di;
}

// ---------------- final: gather t3 (1 feature), bias, sigmoid ----------------
__global__ void k_gather_final(const int* __restrict__ row_start, const int* __restrict__ ssrc,
                               const float* __restrict__ t3, const float* __restrict__ dinv,
                               const float* __restrict__ b_out, float* __restrict__ out) {
    int tid = threadIdx.x;
    int v = blockIdx.x * 16 + (tid >> 4);
    int l = tid & 15;
    int e0 = row_start[v], e1 = row_start[v + 1];
    float sum = 0.0f;
    for (int e = e0 + l; e < e1; e += 16) sum += t3[ssrc[e]];
    sum += __shfl_xor(sum, 1);
    sum += __shfl_xor(sum, 2);
    sum += __shfl_xor(sum, 4);
    sum += __shfl_xor(sum, 8);
    if (l == 0) {
        float z = (sum + t3[v]) * dinv[v] + b_out[0];
        out[v] = 1.0f / (1.0f + expf(-z));
    }
}

extern "C" void kernel_launch(void* const* d_in, const int* in_sizes, int n_in,
                              void* d_out, int out_size, void* d_ws, size_t ws_size,
                              hipStream_t stream) {
    const float* x     = (const float*)d_in[0];
    const int*   ei    = (const int*)d_in[1];   // [2, E] int32
    const float* W_in  = (const float*)d_in[2];
    const float* b_in  = (const float*)d_in[3];
    const float* W_mid = (const float*)d_in[4];
    const float* b_mid = (const float*)d_in[5];
    const float* W_out = (const float*)d_in[6];
    const float* b_out = (const float*)d_in[7];
    float* out = (float*)d_out;

    const int* src = ei;
    const int* dst = ei + NE;

    // workspace layout (≈31 MB)
    char* p = (char*)d_ws;
    int*   cnt       = (int*)p;                 p += sizeof(int) * NN;          // reused as t3
    int*   row_start = (int*)p;                 p += sizeof(int) * (NN + 1);
    int*   fill      = (int*)p;                 p += sizeof(int) * NN;
    int*   bsum      = (int*)p;                 p += sizeof(int) * 1024;
    float* dinv      = (float*)p;               p += sizeof(float) * NN;
    unsigned short* tA = (unsigned short*)p;    p += sizeof(unsigned short) * (size_t)NN * HD;
    unsigned short* tB = (unsigned short*)p;    p += sizeof(unsigned short) * (size_t)NN * HD;
    int*   ssrc      = (int*)p;                 p += sizeof(int) * (size_t)NE;
    float* t3        = (float*)cnt;             // alias: cnt dead after k_scan_final

    const int B = 256;
    const int gE  = (NE + B - 1) / B;       // 18750
    const int gNH = (NN * HD + B - 1) / B;  // 9375
    const int gV  = NN / 16;                // 9375 (one 16-lane group per node)

    // ---- build CSR (counting sort by dst) + dinv ----
    hipMemsetAsync(cnt, 0, sizeof(int) * NN, stream);
    k_hist<<<gE, B, 0, stream>>>(dst, cnt);
    k_bsum<<<NB, B, 0, stream>>>(cnt, bsum);
    k_scan_bsum<<<1, 1024, 0, stream>>>(bsum);
    k_scan_final<<<NB, B, 0, stream>>>(cnt, bsum, row_start, fill, dinv);
    k_scatter_build<<<gE, B, 0, stream>>>(src, dst, fill, ssrc);

    // ---- layer 1: 3 -> 16 ----
    k_transform_in<<<gNH, B, 0, stream>>>(x, W_in, dinv, tA);
    // ---- layer 1 gather + relu + layer-2 transform ----
    k_gather_mid<<<gV, B, 0, stream>>>(row_start, ssrc, tA, dinv, b_in, W_mid, tB);
    // ---- layer 2 gather + relu + output transform (16 -> 1) ----
    k_gather_out<<<gV, B, 0, stream>>>(row_start, ssrc, tB, dinv, b_mid, W_out, t3);
    // ---- layer 3 gather + bias + sigmoid ----
    k_gather_final<<<gV, B, 0, stream>>>(row_start, ssrc, t3, dinv, b_out, out);
}

// Round 4
// 355.928 us; speedup vs baseline: 3.0438x; 2.3725x over previous
//
#include <hip/hip_runtime.h>
#include <math.h>

#define NN 150000      // nodes (== 16 * 9375)
#define NE 4800000     // edges (without self loops)
#define HD 16          // hidden dim
#define NBUCK 586      // ceil(NN / 256) buckets of 256 nodes
#define BSH 8          // bucket shift
#define NBLK 512       // partition blocks
#define CHUNK 9375     // NE / NBLK (exact)
#define NSCAN 300032   // NBUCK * NBLK
#define SCANB 293      // NSCAN / 1024 (exact)

// ---- bf16 helpers (bit-level, round-to-nearest-even) ----
__device__ __forceinline__ float bf2f(unsigned short u) {
    return __uint_as_float(((unsigned int)u) << 16);
}
__device__ __forceinline__ unsigned short f2bf(float f) {
    unsigned int x = __float_as_uint(f);
    return (unsigned short)((x + 0x7FFFu + ((x >> 16) & 1u)) >> 16);
}

// ================= phase A: partition edges into 586 dst-buckets =================

// per-(block,chunk) bucket histogram -> C[b * NBLK + blk]
__global__ __launch_bounds__(256) void k_part_count(const int* __restrict__ dst,
                                                    int* __restrict__ C) {
    __shared__ int h[NBUCK];
    for (int i = threadIdx.x; i < NBUCK; i += 256) h[i] = 0;
    __syncthreads();
    int base = blockIdx.x * CHUNK;
    for (int i = threadIdx.x; i < CHUNK; i += 256)
        atomicAdd(&h[dst[base + i] >> BSH], 1);
    __syncthreads();
    for (int i = threadIdx.x; i < NBUCK; i += 256) C[i * NBLK + blockIdx.x] = h[i];
}

// hierarchical exclusive scan of C (300032 ints, b-major)
__global__ void k_scanA(int* __restrict__ C, int* __restrict__ psum) {
    __shared__ int s[1024];
    int t = threadIdx.x;
    int i = blockIdx.x * 1024 + t;
    int v = C[i];
    s[t] = v;
    __syncthreads();
    for (int off = 1; off < 1024; off <<= 1) {
        int x = (t >= off) ? s[t - off] : 0;
        __syncthreads();
        s[t] += x;
        __syncthreads();
    }
    C[i] = s[t] - v;                      // local exclusive
    if (t == 1023) psum[blockIdx.x] = s[1023];
}

__global__ void k_scanB(int* __restrict__ psum) {
    __shared__ int s[512];
    int t = threadIdx.x;
    int v = (t < SCANB) ? psum[t] : 0;
    s[t] = v;
    __syncthreads();
    for (int off = 1; off < 512; off <<= 1) {
        int x = (t >= off) ? s[t - off] : 0;
        __syncthreads();
        s[t] += x;
        __syncthreads();
    }
    if (t < SCANB) psum[t] = s[t] - v;    // exclusive
}

__global__ void k_scanC(int* __restrict__ C, const int* __restrict__ psum,
                        int* __restrict__ bstart) {
    int i = blockIdx.x * 1024 + threadIdx.x;
    int v = C[i] + psum[blockIdx.x];
    C[i] = v;
    if ((i & (NBLK - 1)) == 0) bstart[i >> 9] = v;   // (b, blk=0) -> bucket base
    if (i == 0) bstart[NBUCK] = NE;
}

// scatter edges to bucket-grouped packed array; each block owns a private run
// per bucket (C[b*NBLK+blk]) -> coalesced runs, no global position atomics
__global__ __launch_bounds__(256) void k_part_scatter(const int* __restrict__ src,
                                                      const int* __restrict__ dst,
                                                      const int* __restrict__ C,
                                                      int* __restrict__ packed) {
    __shared__ int cur[NBUCK];
    for (int i = threadIdx.x; i < NBUCK; i += 256) cur[i] = C[i * NBLK + blockIdx.x];
    __syncthreads();
    int base = blockIdx.x * CHUNK;
    for (int i = threadIdx.x; i < CHUNK; i += 256) {
        int s = src[base + i], d = dst[base + i];
        int pos = atomicAdd(&cur[d >> BSH], 1);
        packed[pos] = (s << BSH) | (d & 255);   // src < 2^18, local dst < 2^8
    }
}

// ================= phase B: per-bucket local counting sort =================
// one block per bucket; emits row_start, dinv, and dst-sorted ssrc
__global__ __launch_bounds__(256) void k_bucket_sort(const int* __restrict__ packed,
                                                     const int* __restrict__ bstart,
                                                     int* __restrict__ row_start,
                                                     float* __restrict__ dinv,
                                                     int* __restrict__ ssrc) {
    __shared__ int hist[256];
    __shared__ int fill[256];
    int b = blockIdx.x;
    int t = threadIdx.x;
    int v0 = b << BSH;
    int nv = min(256, NN - v0);
    int e0 = bstart[b], e1 = bstart[b + 1];
    hist[t] = 0;
    __syncthreads();
    for (int e = e0 + t; e < e1; e += 256)
        atomicAdd(&hist[packed[e] & 255], 1);
    __syncthreads();
    int cv = hist[t];
    __syncthreads();
    for (int off = 1; off < 256; off <<= 1) {
        int x = (t >= off) ? hist[t - off] : 0;
        __syncthreads();
        hist[t] += x;
        __syncthreads();
    }
    int excl = hist[t] - cv;
    if (t < nv) {
        row_start[v0 + t] = e0 + excl;
        fill[t] = e0 + excl;
        dinv[v0 + t] = rsqrtf((float)cv + 1.0f);   // +1: self loop
    }
    __syncthreads();
    for (int e = e0 + t; e < e1; e += 256) {
        int p = packed[e];
        int pos = atomicAdd(&fill[p & 255], 1);
        ssrc[pos] = p >> BSH;
    }
    if (b == 0 && t == 0) row_start[NN] = NE;
}

// ================= layer 1 transform: t = (x @ W_in) * dinv (bf16 out) =================
__global__ __launch_bounds__(256) void k_transform_in(const float* __restrict__ x,
                                                      const float* __restrict__ W,
                                                      const float* __restrict__ dinv,
                                                      unsigned short* __restrict__ t) {
    int gid = blockIdx.x * blockDim.x + threadIdx.x;
    if (gid >= NN * HD) return;
    int v = gid >> 4, j = gid & 15;
    float s = x[v * 3 + 0] * W[j] + x[v * 3 + 1] * W[HD + j] + x[v * 3 + 2] * W[2 * HD + j];
    t[gid] = f2bf(s * dinv[v]);
}

// ============ fused gather + relu + next transform (16 -> 16), 16 lanes/node ============
__global__ __launch_bounds__(256) void k_gather_mid(const int* __restrict__ row_start,
                                                    const int* __restrict__ ssrc,
                                                    const unsigned short* __restrict__ t,
                                                    const float* __restrict__ dinv,
                                                    const float* __restrict__ b,
                                                    const float* __restrict__ W,
                                                    unsigned short* __restrict__ tnext) {
    __shared__ float sW[HD * HD];
    __shared__ float sh[256];
    int tid = threadIdx.x;
    sW[tid] = W[tid];
    int v = blockIdx.x * 16 + (tid >> 4);
    int j = tid & 15;
    int e0 = row_start[v], e1 = row_start[v + 1];
    float sum = 0.0f;
    int e = e0;
    for (; e + 4 <= e1; e += 4) {
        int s0 = ssrc[e], s1 = ssrc[e + 1], s2 = ssrc[e + 2], s3 = ssrc[e + 3];
        sum += bf2f(t[s0 * HD + j]) + bf2f(t[s1 * HD + j])
             + bf2f(t[s2 * HD + j]) + bf2f(t[s3 * HD + j]);
    }
    for (; e < e1; ++e) sum += bf2f(t[ssrc[e] * HD + j]);
    sum += bf2f(t[v * HD + j]);                 // self loop
    float di = dinv[v];
    float h = fmaxf(sum * di + b[j], 0.0f);
    sh[tid] = h;
    __syncthreads();
    int g = tid & 240;                          // group base (tid>>4)<<4
    float o = 0.0f;
#pragma unroll
    for (int k = 0; k < HD; ++k) o += sh[g + k] * sW[k * HD + j];
    tnext[v * HD + j] = f2bf(o * di);
}

// ============ fused gather + relu + output dot (16 -> 1) ============
__global__ __launch_bounds__(256) void k_gather_out(const int* __restrict__ row_start,
                                                    const int* __restrict__ ssrc,
                                                    const unsigned short* __restrict__ t,
                                                    const float* __restrict__ dinv,
                                                    const float* __restrict__ b,
                                                    const float* __restrict__ Wout,
                                                    float* __restrict__ t3) {
    int tid = threadIdx.x;
    int v = blockIdx.x * 16 + (tid >> 4);
    int j = tid & 15;
    int e0 = row_start[v], e1 = row_start[v + 1];
    float sum = 0.0f;
    int e = e0;
    for (; e + 4 <= e1; e += 4) {
        int s0 = ssrc[e], s1 = ssrc[e + 1], s2 = ssrc[e + 2], s3 = ssrc[e + 3];
        sum += bf2f(t[s0 * HD + j]) + bf2f(t[s1 * HD + j])
             + bf2f(t[s2 * HD + j]) + bf2f(t[s3 * HD + j]);
    }
    for (; e < e1; ++e) sum += bf2f(t[ssrc[e] * HD + j]);
    sum += bf2f(t[v * HD + j]);
    float di = dinv[v];
    float h = fmaxf(sum * di + b[j], 0.0f);
    float d = h * Wout[j];
    d += __shfl_xor(d, 1);
    d += __shfl_xor(d, 2);
    d += __shfl_xor(d, 4);
    d += __shfl_xor(d, 8);
    if (j == 0) t3[v] = d * di;
}

// ============ final: gather t3 (1 feature), bias, sigmoid ============
__global__ __launch_bounds__(256) void k_gather_final(const int* __restrict__ row_start,
                                                      const int* __restrict__ ssrc,
                                                      const float* __restrict__ t3,
                                                      const float* __restrict__ dinv,
                                                      const float* __restrict__ b_out,
                                                      float* __restrict__ out) {
    int tid = threadIdx.x;
    int v = blockIdx.x * 16 + (tid >> 4);
    int l = tid & 15;
    int e0 = row_start[v], e1 = row_start[v + 1];
    float sum = 0.0f;
    for (int e = e0 + l; e < e1; e += 16) sum += t3[ssrc[e]];
    sum += __shfl_xor(sum, 1);
    sum += __shfl_xor(sum, 2);
    sum += __shfl_xor(sum, 4);
    sum += __shfl_xor(sum, 8);
    if (l == 0) {
        float z = (sum + t3[v]) * dinv[v] + b_out[0];
        out[v] = 1.0f / (1.0f + expf(-z));
    }
}

extern "C" void kernel_launch(void* const* d_in, const int* in_sizes, int n_in,
                              void* d_out, int out_size, void* d_ws, size_t ws_size,
                              hipStream_t stream) {
    const float* x     = (const float*)d_in[0];
    const int*   ei    = (const int*)d_in[1];
    const float* W_in  = (const float*)d_in[2];
    const float* b_in  = (const float*)d_in[3];
    const float* W_mid = (const float*)d_in[4];
    const float* b_mid = (const float*)d_in[5];
    const float* W_out = (const float*)d_in[6];
    const float* b_out = (const float*)d_in[7];
    float* out = (float*)d_out;

    const int* src = ei;
    const int* dst = ei + NE;

    // workspace layout (~41 MB): tA/tB/t3 alias the packed buffer (dead after bucket_sort)
    char* p = (char*)d_ws;
    int*   C         = (int*)p;      p += sizeof(int) * NSCAN;        // 1.2 MB
    int*   psum      = (int*)p;      p += sizeof(int) * 512;
    int*   bstart    = (int*)p;      p += sizeof(int) * (NBUCK + 1);
    int*   row_start = (int*)p;      p += sizeof(int) * (NN + 1);
    float* dinv      = (float*)p;    p += sizeof(float) * NN;
    int*   ssrc      = (int*)p;      p += sizeof(int) * (size_t)NE;   // 19.2 MB
    int*   packed    = (int*)p;      p += sizeof(int) * (size_t)NE;   // 19.2 MB
    unsigned short* tA = (unsigned short*)packed;                      // 4.8 MB  (alias)
    unsigned short* tB = tA + (size_t)NN * HD;                         // 4.8 MB  (alias)
    float* t3          = (float*)(tB + (size_t)NN * HD);               // 0.6 MB  (alias)

    const int B = 256;
    const int gNH = (NN * HD + B - 1) / B;  // 9375
    const int gV  = NN / 16;                // 9375

    // ---- build dst-sorted CSR via two-level counting sort ----
    k_part_count<<<NBLK, B, 0, stream>>>(dst, C);
    k_scanA<<<SCANB, 1024, 0, stream>>>(C, psum);
    k_scanB<<<1, 512, 0, stream>>>(psum);
    k_scanC<<<SCANB, 1024, 0, stream>>>(C, psum, bstart);
    k_part_scatter<<<NBLK, B, 0, stream>>>(src, dst, C, packed);
    k_bucket_sort<<<NBUCK, B, 0, stream>>>(packed, bstart, row_start, dinv, ssrc);

    // ---- layers ----
    k_transform_in<<<gNH, B, 0, stream>>>(x, W_in, dinv, tA);
    k_gather_mid<<<gV, B, 0, stream>>>(row_start, ssrc, tA, dinv, b_in, W_mid, tB);
    k_gather_out<<<gV, B, 0, stream>>>(row_start, ssrc, tB, dinv, b_mid, W_out, t3);
    k_gather_final<<<gV, B, 0, stream>>>(row_start, ssrc, t3, dinv, b_out, out);
}